// Round 1
// baseline (503.908 us; speedup 1.0000x reference)
//
#include <hip/hip_runtime.h>
#include <stdint.h>

#define N_NODES 4096
#define F_DIM   64
#define LRELU_ALPHA 0.2f

typedef unsigned short u16;
typedef __attribute__((ext_vector_type(8))) short short8;   // 8 bf16 = 4 VGPRs (MFMA A/B frag)
typedef __attribute__((ext_vector_type(4))) float f32x4;    // MFMA C/D frag

__device__ __forceinline__ u16 bf16_trunc(float x) {
  return (u16)(__float_as_uint(x) >> 16);
}

// ---------------------------------------------------------------------------
// Kernel 1: Wh = h @ W ; ei = Wh·a1 ; ej = Wh·a2 ;
//           WhT_hi/lo[b][f][n] = split-bf16 transpose of Wh (B-operand layout)
// grid 256 blocks x 256 thr; block = 64 rows (wave = 16 rows), lane = f.
// ---------------------------------------------------------------------------
__global__ __launch_bounds__(256) void gat_prep(
    const float* __restrict__ h, const float* __restrict__ W,
    const float* __restrict__ a, float* __restrict__ ei,
    float* __restrict__ ej, u16* __restrict__ whT_hi,
    u16* __restrict__ whT_lo)
{
  __shared__ float lds_h[4][F_DIM];
  const int t    = threadIdx.x;
  const int w    = t >> 6;
  const int lane = t & 63;
  const int b    = blockIdx.x >> 6;          // 64 blocks per batch
  const int n0   = (blockIdx.x & 63) * 64;   // 64 rows per block

  // W column for this lane, kept in registers (L1/L2-hot across blocks)
  float wcol[F_DIM];
#pragma unroll
  for (int k = 0; k < F_DIM; ++k) wcol[k] = W[k * F_DIM + lane];

  const float a1 = a[lane];
  const float a2 = a[F_DIM + lane];

  for (int r = 0; r < 16; ++r) {
    const int n = n0 + w * 16 + r;
    const float hv = h[((size_t)b * N_NODES + n) * F_DIM + lane];
    lds_h[w][lane] = hv;            // in-wave write->read; compiler inserts lgkmcnt
    float wh = 0.f;
#pragma unroll
    for (int k = 0; k < F_DIM; k += 4) {
      const float4 hb = *(const float4*)(&lds_h[w][k]);   // broadcast read
      wh = fmaf(hb.x, wcol[k + 0], wh);
      wh = fmaf(hb.y, wcol[k + 1], wh);
      wh = fmaf(hb.z, wcol[k + 2], wh);
      wh = fmaf(hb.w, wcol[k + 3], wh);
    }
    // ei/ej: full-wave reduction of wh*a
    float s1 = wh * a1, s2 = wh * a2;
#pragma unroll
    for (int off = 32; off >= 1; off >>= 1) {
      s1 += __shfl_xor(s1, off);
      s2 += __shfl_xor(s2, off);
    }
    if (lane == 0) {
      ei[b * N_NODES + n] = s1;
      ej[b * N_NODES + n] = s2;
    }
    // split bf16 (truncation; lo captures the residual)
    const uint32_t u = __float_as_uint(wh);
    const u16 hi = (u16)(u >> 16);
    const float hif = __uint_as_float(u & 0xFFFF0000u);
    const u16 lo = bf16_trunc(wh - hif);
    const size_t o = ((size_t)b * F_DIM + lane) * N_NODES + n;  // [b][f][n]
    whT_hi[o] = hi;   // 2B scattered stores; L2 merges rows n0..n0+15 per line
    whT_lo[o] = lo;
  }
}

// ---------------------------------------------------------------------------
// Kernel 2: fused masked-softmax attention + PV via split-bf16 MFMA.
// grid 1024 blocks x 256 thr; block = one (b, 16-row i-tile); wave w owns
// j in [w*1024, (w+1)*1024). P built directly in A-frag layout:
//   A[m=lane&15][k=quad*8+x], j = jk + x. B[k][n=lane&15] from WhT[b][f][j].
// C/D layout: col=lane&15, row=quad*4+reg  (HW-verified m89/m91).
// No online max needed: logits bounded (std~2.6), exp() safe in fp32.
// ---------------------------------------------------------------------------
__global__ __launch_bounds__(256, 4) void gat_attn(
    const int* __restrict__ adj, const float* __restrict__ ei,
    const float* __restrict__ ej, const u16* __restrict__ whT_hi,
    const u16* __restrict__ whT_lo, float* __restrict__ out)
{
  __shared__ float num_lds[4][16][F_DIM];
  __shared__ float den_lds[4][16];

  const int t    = threadIdx.x;
  const int w    = t >> 6;
  const int lane = t & 63;
  const int quad = lane >> 4;
  const int m    = lane & 15;

  const int b  = blockIdx.x >> 8;            // 256 i-tiles per batch
  const int i0 = (blockIdx.x & 255) * 16;
  const int i  = i0 + m;

  const float ei_s = ei[b * N_NODES + i];
  const int jstart = w * (N_NODES / 4);

  const float* ejb     = ej + b * N_NODES;
  const int*   adj_row = adj + ((size_t)b * N_NODES + i) * N_NODES;
  const u16*   hi_b    = whT_hi + ((size_t)b * F_DIM + m) * N_NODES;
  const u16*   lo_b    = whT_lo + ((size_t)b * F_DIM + m) * N_NODES;

  f32x4 acc[4] = {{0.f,0.f,0.f,0.f},{0.f,0.f,0.f,0.f},
                  {0.f,0.f,0.f,0.f},{0.f,0.f,0.f,0.f}};
  float den = 0.f;

  for (int jc = 0; jc < (N_NODES / 4) / 32; ++jc) {
    const int jk = jstart + jc * 32 + quad * 8;   // this lane's 8 j's

    float ejArr[8];
    *(float4*)(&ejArr[0]) = *(const float4*)(ejb + jk);
    *(float4*)(&ejArr[4]) = *(const float4*)(ejb + jk + 4);
    int adjArr[8];
    *(int4*)(&adjArr[0]) = *(const int4*)(adj_row + jk);
    *(int4*)(&adjArr[4]) = *(const int4*)(adj_row + jk + 4);

    short8 bh[4], bl[4];
#pragma unroll
    for (int fc = 0; fc < 4; ++fc) {
      const size_t o = (size_t)(fc * 16) * N_NODES + jk;
      bh[fc] = *(const short8*)(hi_b + o);
      bl[fc] = *(const short8*)(lo_b + o);
    }

    short8 phi, plo;
#pragma unroll
    for (int x = 0; x < 8; ++x) {
      float e = ei_s + ejArr[x];
      e = fmaxf(e, LRELU_ALPHA * e);               // leaky-relu
      const float p = (adjArr[x] > 0) ? __expf(e) : 0.f;
      den += p;
      const uint32_t u = __float_as_uint(p);
      phi[x] = (short)(u >> 16);
      const float hif = __uint_as_float(u & 0xFFFF0000u);
      plo[x] = (short)(__float_as_uint(p - hif) >> 16);
    }

#pragma unroll
    for (int fc = 0; fc < 4; ++fc) {
      acc[fc] = __builtin_amdgcn_mfma_f32_16x16x32_bf16(phi, bh[fc], acc[fc], 0, 0, 0);
      acc[fc] = __builtin_amdgcn_mfma_f32_16x16x32_bf16(plo, bh[fc], acc[fc], 0, 0, 0);
      acc[fc] = __builtin_amdgcn_mfma_f32_16x16x32_bf16(phi, bl[fc], acc[fc], 0, 0, 0);
    }
  }

  // den: sum the 4 lane-groups holding the same row
  den += __shfl_xor(den, 16);
  den += __shfl_xor(den, 32);

  // stash per-wave partials
#pragma unroll
  for (int fc = 0; fc < 4; ++fc)
#pragma unroll
    for (int reg = 0; reg < 4; ++reg)
      num_lds[w][quad * 4 + reg][fc * 16 + m] = acc[fc][reg];
  if (lane < 16) den_lds[w][lane] = den;
  __syncthreads();

  // cross-wave reduce + softmax divide + ELU + store (coalesced)
#pragma unroll
  for (int k = 0; k < 4; ++k) {
    const int idx = k * 256 + t;       // 1024 outputs = 16 rows x 64 f
    const int il = idx >> 6;
    const int f  = idx & 63;
    const float num = num_lds[0][il][f] + num_lds[1][il][f] +
                      num_lds[2][il][f] + num_lds[3][il][f];
    const float d = den_lds[0][il] + den_lds[1][il] +
                    den_lds[2][il] + den_lds[3][il];
    float v = (d > 0.f) ? (num / d) : 0.f;
    v = (v > 0.f) ? v : (__expf(v) - 1.f);         // elu
    out[((size_t)b * N_NODES + i0 + il) * F_DIM + f] = v;
  }
}

extern "C" void kernel_launch(void* const* d_in, const int* in_sizes, int n_in,
                              void* d_out, int out_size, void* d_ws, size_t ws_size,
                              hipStream_t stream) {
  const float* h   = (const float*)d_in[0];
  const int*   adj = (const int*)d_in[1];
  const float* W   = (const float*)d_in[2];
  const float* a   = (const float*)d_in[3];
  float* out = (float*)d_out;

  char* ws = (char*)d_ws;
  float* ei      = (float*)ws;                          // 4*4096*4   = 64 KB
  float* ej      = (float*)(ws + 65536);                // 64 KB
  u16*   whT_hi  = (u16*)(ws + 131072);                 // 4*64*4096*2 = 2 MB
  u16*   whT_lo  = (u16*)(ws + 131072 + 2097152);       // 2 MB

  hipLaunchKernelGGL(gat_prep, dim3(256), dim3(256), 0, stream,
                     h, W, a, ei, ej, whT_hi, whT_lo);
  hipLaunchKernelGGL(gat_attn, dim3(1024), dim3(256), 0, stream,
                     adj, ei, ej, whT_hi, whT_lo, out);
}

// Round 4
// 416.413 us; speedup vs baseline: 1.2101x; 1.2101x over previous
//
#include <hip/hip_runtime.h>
#include <stdint.h>

#define N_NODES 4096
#define F_DIM   64
#define LRELU_ALPHA 0.2f

typedef _Float16 f16;
typedef __attribute__((ext_vector_type(8))) _Float16 half8;  // MFMA f16 A/B frag (4 VGPRs)
typedef __attribute__((ext_vector_type(4))) float f32x4;     // MFMA C/D frag

// ---------------------------------------------------------------------------
// Kernel 1: Wh = h@W (fp32 VALU); ei=Wh·a1, ej=Wh·a2; wh16[b][f][n] = (f16)Wh
// (transposed via LDS for coalesced stores); blockmax[blk] = max ej over the
// block's 16 rows (plain store — no atomics, no memset needed).
// grid 1024 x 256 (4 blocks/CU); wave = 4 rows.
// ---------------------------------------------------------------------------
__global__ __launch_bounds__(256) void gat_prep(
    const float* __restrict__ h, const float* __restrict__ W,
    const float* __restrict__ a, float* __restrict__ ei,
    float* __restrict__ ej, f16* __restrict__ wh16,
    float* __restrict__ blockmax)
{
  __shared__ float sh_h[4][F_DIM];
  __shared__ f16 tile[F_DIM][16];   // [f][local n]
  __shared__ float wmax[4];
  const int t = threadIdx.x, w = t >> 6, lane = t & 63;
  const int n0 = blockIdx.x * 16;       // global row base (0..16383)
  const int b  = n0 >> 12;
  const int nl0 = n0 & (N_NODES - 1);   // row base within batch

  float wcol[F_DIM];
#pragma unroll
  for (int k = 0; k < F_DIM; ++k) wcol[k] = W[k * F_DIM + lane];
  const float a1 = a[lane], a2 = a[F_DIM + lane];

  float runmax = -3e38f;
  for (int r = 0; r < 4; ++r) {
    const int loc = w * 4 + r;
    const int n = n0 + loc;
    const float hv = h[(size_t)n * F_DIM + lane];
    sh_h[w][lane] = hv;                       // same-wave LDS write->read (in-order pipe)
    float wh = 0.f;
#pragma unroll
    for (int k = 0; k < F_DIM; k += 4) {
      const float4 hb = *(const float4*)(&sh_h[w][k]);
      wh = fmaf(hb.x, wcol[k + 0], wh);
      wh = fmaf(hb.y, wcol[k + 1], wh);
      wh = fmaf(hb.z, wcol[k + 2], wh);
      wh = fmaf(hb.w, wcol[k + 3], wh);
    }
    float s1 = wh * a1, s2 = wh * a2;
#pragma unroll
    for (int off = 32; off; off >>= 1) {
      s1 += __shfl_xor(s1, off);
      s2 += __shfl_xor(s2, off);
    }
    if (lane == 0) { ei[n] = s1; ej[n] = s2; }
    runmax = fmaxf(runmax, s2);               // s2 identical on all lanes
    tile[lane][loc] = (f16)wh;                // f = lane
  }
  if (lane == 0) wmax[w] = runmax;
  __syncthreads();

  // coalesced f16 store: thread t -> f = t>>2, 8B chunk part = t&3
  {
    const int f = t >> 2, part = t & 3;
    *(uint2*)(wh16 + ((size_t)(b * F_DIM + f)) * N_NODES + nl0 + part * 4) =
        *(const uint2*)(&tile[f][part * 4]);
  }
  if (t == 0)
    blockmax[blockIdx.x] =
        fmaxf(fmaxf(wmax[0], wmax[1]), fmaxf(wmax[2], wmax[3]));
}

// ---------------------------------------------------------------------------
// Kernel 2: fused masked-softmax attention + PV (f16 MFMA) + ELU, direct out.
// block = (b, 16-row i-tile), 512 threads = 8 waves; wave w sweeps j in
// [w*512, (w+1)*512). grid 1024 -> 4 blocks/CU = 32 waves/CU (occupancy-
// driven: round-1 was latency-bound at 42%). In-block LDS reduction merges
// the 8 j-partials; no global accumulators, no atomics.
// Range control: p' = exp(leaky(e) - bnd), bnd = leaky(ei + maxej_batch)
// >= row max (leaky monotone) -> p' in (0,1], f16-safe; shift cancels in
// num/den. A-frag: A[m=lane&15][k=quad*8+x]; B-frag: B[k][n=lane&15];
// C/D: row=quad*4+reg, col=lane&15 (HW-verified m89/m91).
// ---------------------------------------------------------------------------
__global__ __launch_bounds__(512, 6) void gat_attn(
    const int* __restrict__ adj, const float* __restrict__ ei,
    const float* __restrict__ ej, const f16* __restrict__ wh16,
    const float* __restrict__ blockmax, float* __restrict__ out)
{
  __shared__ float num_lds[8][16][F_DIM];   // 32 KB
  __shared__ float den_lds[8][16];          // 512 B

  const int t = threadIdx.x, w = t >> 6, lane = t & 63;
  const int quad = lane >> 4, m = lane & 15;
  const int b  = blockIdx.x >> 8;            // 256 i-tiles per batch
  const int i0 = (blockIdx.x & 255) * 16;
  const int i  = i0 + m;
  const int rowg = b * N_NODES + i;

  // per-batch max(ej): reduce 256 plain-stored per-block maxima (L2-hot)
  float maxej;
  {
    const float4 v = *(const float4*)(blockmax + b * 256 + lane * 4);
    maxej = fmaxf(fmaxf(v.x, v.y), fmaxf(v.z, v.w));
#pragma unroll
    for (int off = 32; off; off >>= 1)
      maxej = fmaxf(maxej, __shfl_xor(maxej, off));
  }

  const float ei_s = ei[rowg];
  float bnd = ei_s + maxej;
  bnd = fmaxf(bnd, LRELU_ALPHA * bnd);       // leaky(ei + maxej) >= row max logit

  const float* ejb     = ej + b * N_NODES;
  const int*   adj_row = adj + (size_t)rowg * N_NODES;
  const f16*   whb     = wh16 + ((size_t)(b * F_DIM + m)) * N_NODES;

  f32x4 acc[4] = {{0.f,0.f,0.f,0.f},{0.f,0.f,0.f,0.f},
                  {0.f,0.f,0.f,0.f},{0.f,0.f,0.f,0.f}};
  float den = 0.f;
  const int jbase = w * (N_NODES / 8);       // this wave's 512-j window

  for (int jc = 0; jc < 16; ++jc) {
    const int jk = jbase + jc * 32 + quad * 8;

    float ejA[8];
    *(float4*)(&ejA[0]) = *(const float4*)(ejb + jk);
    *(float4*)(&ejA[4]) = *(const float4*)(ejb + jk + 4);
    int adA[8];
    *(int4*)(&adA[0]) = *(const int4*)(adj_row + jk);
    *(int4*)(&adA[4]) = *(const int4*)(adj_row + jk + 4);

    half8 bf[4];
#pragma unroll
    for (int fc = 0; fc < 4; ++fc)
      bf[fc] = *(const half8*)(whb + (size_t)(fc * 16) * N_NODES + jk);

    half8 pa;
#pragma unroll
    for (int x = 0; x < 8; ++x) {
      float e = ei_s + ejA[x];
      e = fmaxf(e, LRELU_ALPHA * e);
      const float p = (adA[x] > 0) ? __expf(e - bnd) : 0.f;
      pa[x] = (f16)p;
      den += (float)pa[x];     // accumulate the SAME quantized value MFMA sees
    }

#pragma unroll
    for (int fc = 0; fc < 4; ++fc)
      acc[fc] = __builtin_amdgcn_mfma_f32_16x16x32_f16(pa, bf[fc], acc[fc], 0, 0, 0);
  }

  // den: lanes sharing a row (same lane&15) live 16 apart
  den += __shfl_xor(den, 16);
  den += __shfl_xor(den, 32);
  if (lane < 16) den_lds[w][lane] = den;

#pragma unroll
  for (int fc = 0; fc < 4; ++fc)
#pragma unroll
    for (int rg = 0; rg < 4; ++rg)
      num_lds[w][quad * 4 + rg][fc * 16 + m] = acc[fc][rg];
  __syncthreads();

  // merge 8 wave-partials, divide, ELU, coalesced store (1024 outs, 512 thr)
#pragma unroll
  for (int k = 0; k < 2; ++k) {
    const int idx = k * 512 + t;
    const int il = idx >> 6, f = idx & 63;
    float num = 0.f, d = 0.f;
#pragma unroll
    for (int ww = 0; ww < 8; ++ww) {
      num += num_lds[ww][il][f];
      d   += den_lds[ww][il];
    }
    float v = (d > 0.f) ? (num / d) : 0.f;
    v = (v > 0.f) ? v : expm1f(v);
    out[((size_t)(b * N_NODES + i0 + il)) * F_DIM + f] = v;
  }
}

extern "C" void kernel_launch(void* const* d_in, const int* in_sizes, int n_in,
                              void* d_out, int out_size, void* d_ws, size_t ws_size,
                              hipStream_t stream) {
  const float* h   = (const float*)d_in[0];
  const int*   adj = (const int*)d_in[1];
  const float* W   = (const float*)d_in[2];
  const float* a   = (const float*)d_in[3];
  float* out = (float*)d_out;

  char* ws = (char*)d_ws;
  // Workspace (2.14 MB total — well inside the 4.33 MB proven in round 1):
  // [0,       +64 KB)  ei
  // [65536,   +64 KB)  ej
  // [131072,  +4 KB)   blockmax (1024 floats, fully written by gat_prep)
  // [135168,  +2 MB)   wh16
  float* ei       = (float*)ws;
  float* ej       = (float*)(ws + 65536);
  float* blockmax = (float*)(ws + 131072);
  f16*   wh16     = (f16*)(ws + 135168);

  hipLaunchKernelGGL(gat_prep, dim3(1024), dim3(256), 0, stream,
                     h, W, a, ei, ej, wh16, blockmax);
  hipLaunchKernelGGL(gat_attn, dim3(1024), dim3(512), 0, stream,
                     adj, ei, ej, wh16, blockmax, out);
}